// Round 1
// 303.816 us; speedup vs baseline: 1.0332x; 1.0332x over previous
//
#include <hip/hip_runtime.h>
#include <math.h>

// ---------------------------------------------------------------------------
// SparseMoE — MFMA kernel, MI355X (gfx950).  B=8 S=4096 D=256 F=512 E=8 K=2.
// r10: latency/occupancy attack on the r8/r9 skeleton (182us main, 22% occ):
//   * Yb LDS epilogue removed -> register LayerNorm (xor-shuffle over c-lanes
//     + 1KB cross-wave reduce).  Kills the 8-way bank conflicts (9.8M) and
//     33KB of LDS.
//   * Hsb double-buffered -> 1 barrier per fb (was 2); next fb's W1 loads
//     hoist into previous GEMM2's compute shadow.
//   * W2 B-fragments prefetched to registers BEFORE the barrier -> GEMM2
//     never waits on global latency post-barrier.
//   * LDS 56.8KB -> ~29KB, __launch_bounds__(256,4): grid 1024 fully
//     resident at 4 blocks/CU (16 waves/CU).
//   * Launch fusion 6 -> 3 kernels: k_prep (reduce1 + both W transposes),
//     k_finish (reduce2 + fp64 router, bitwise-identical arithmetic), k_moe_m.
// Router fp64 deterministic (unchanged).  ws ~5.3 MB.
// ---------------------------------------------------------------------------

#define B_ 8
#define S_ 4096
#define D_ 256
#define F_ 512
#define E_ 8

typedef short bf16x8 __attribute__((ext_vector_type(8)));
typedef float f32x4 __attribute__((ext_vector_type(4)));

static __device__ __forceinline__ unsigned short f2bf(float f) {
    union { float f; unsigned int i; } v; v.f = f;
    unsigned int x = v.i;
    return (unsigned short)((x + 0x7fffu + ((x >> 16) & 1u)) >> 16);  // RNE
}
static __device__ __forceinline__ float bf2f(unsigned short u) {
    union { unsigned int i; float f; } v; v.i = ((unsigned int)u) << 16; return v.f;
}

// ---------------------------------------------------------------------------
// 1) k_prep: fused grid. Blocks [0,512): fp64 partial mean-reduction over S.
//    Blocks [512,1536): W1 [E][256][512] -> W1T [E][512][256] bf16.
//    Blocks [1536,2560): W2 [E][512][256] -> W2T [E][256][512] bf16.
// ---------------------------------------------------------------------------
__global__ void k_prep(const float* __restrict__ x,
                       double* __restrict__ partial,
                       const float* __restrict__ W1,
                       const float* __restrict__ W2,
                       unsigned short* __restrict__ W1T,
                       unsigned short* __restrict__ W2T) {
    int bid = blockIdx.x;
    if (bid < 512) {
        int b = bid >> 6;
        int c = bid & 63;
        int d = threadIdx.x;
        const float* p = x + ((size_t)(b * S_ + c * 64) * D_ + d);
        double acc = 0.0;
        #pragma unroll 8
        for (int i = 0; i < 64; ++i) acc += (double)p[(size_t)i * D_];
        partial[(size_t)bid * D_ + d] = acc;
        return;
    }
    __shared__ float tile[32][33];
    const float* src;
    unsigned short* dst;
    int R, C, cb, rb;
    if (bid < 1536) {
        int b2 = bid - 512;            // e(8) x by(8) x bx(16)
        int e = b2 >> 7, rem = b2 & 127;
        int by = rem >> 4, bx = rem & 15;
        R = 256; C = 512;
        src = W1 + (size_t)e * R * C;
        dst = W1T + (size_t)e * R * C;
        cb = bx * 32; rb = by * 32;
    } else {
        int b2 = bid - 1536;           // e(8) x by(16) x bx(8)
        int e = b2 >> 7, rem = b2 & 127;
        int by = rem >> 3, bx = rem & 7;
        R = 512; C = 256;
        src = W2 + (size_t)e * R * C;
        dst = W2T + (size_t)e * R * C;
        cb = bx * 32; rb = by * 32;
    }
    int tx = threadIdx.x & 31, ty = threadIdx.x >> 5;
    #pragma unroll
    for (int k = 0; k < 4; ++k)
        tile[ty + 8 * k][tx] = src[(size_t)(rb + ty + 8 * k) * C + cb + tx];
    __syncthreads();
    #pragma unroll
    for (int k = 0; k < 4; ++k)
        dst[(size_t)(cb + ty + 8 * k) * R + rb + tx] = f2bf(tile[tx][ty + 8 * k]);
}

// ---------------------------------------------------------------------------
// 2) k_finish: reduce2 + fp64 router in ONE block (bitwise-identical order
//    to the r8-proven k_reduce2 + k_router pair).
// ---------------------------------------------------------------------------
__global__ void k_finish(const double* __restrict__ partial,
                         const float* __restrict__ Wr,
                         const float* __restrict__ br,
                         float* __restrict__ route) {
    __shared__ double xs[8][256];
    __shared__ double lg[64];
    int t = threadIdx.x;
    for (int bb = 0; bb < 8; ++bb) {
        double acc = 0.0;
        #pragma unroll 8
        for (int c = 0; c < 64; ++c)
            acc += partial[(size_t)(bb * 64 + c) * D_ + t];
        xs[bb][t] = acc;
    }
    __syncthreads();
    if (t < 64) {
        int b = t >> 3, e = t & 7;
        double acc = 0.0;
        for (int d = 0; d < D_; ++d)
            acc += (xs[b][d] * (1.0 / (double)S_)) * (double)Wr[d * E_ + e];
        lg[t] = acc + (double)br[e];
    }
    __syncthreads();
    if (t == 0) {
        double rw[8][8];
        for (int bb = 0; bb < 8; ++bb) {
            double m = -1e300;
            for (int ee = 0; ee < 8; ++ee) m = fmax(m, lg[bb * 8 + ee]);
            double s = 0.0;
            for (int ee = 0; ee < 8; ++ee) { double p = exp(lg[bb * 8 + ee] - m); rw[bb][ee] = p; s += p; }
            for (int ee = 0; ee < 8; ++ee) rw[bb][ee] /= s;
        }
        const double capacity = 5120.0;
        double scale[8];
        for (int ee = 0; ee < 8; ++ee) {
            double load = 0.0;
            for (int bb = 0; bb < 8; ++bb) load += rw[bb][ee];
            load *= 4096.0;
            scale[ee] = load > capacity ? capacity / load : 1.0;
        }
        for (int bb = 0; bb < 8; ++bb) {
            double v[8];
            double m = -1e300;
            for (int ee = 0; ee < 8; ++ee) { v[ee] = rw[bb][ee] * scale[ee]; m = fmax(m, v[ee]); }
            double s = 0.0;
            for (int ee = 0; ee < 8; ++ee) { v[ee] = exp(v[ee] - m); s += v[ee]; }
            for (int ee = 0; ee < 8; ++ee) v[ee] /= s;
            int i1 = 0;
            for (int ee = 1; ee < 8; ++ee) if (v[ee] > v[i1]) i1 = ee;
            int i2 = (i1 == 0) ? 1 : 0;
            for (int ee = 0; ee < 8; ++ee) { if (ee == i1) continue; if (v[ee] > v[i2]) i2 = ee; }
            double d21 = v[i2] - v[i1];
            double ed = exp(d21);
            double w1 = 1.0 / (1.0 + ed);
            double w2 = ed * w1;
            route[bb * 4 + 0] = (float)i1;
            route[bb * 4 + 1] = (float)i2;
            route[bb * 4 + 2] = (float)w1;
            route[bb * 4 + 3] = (float)w2;
        }
    }
}

// ---------------------------------------------------------------------------
// 3) Main MFMA kernel: per block = (batch, 32-token tile). 1024 x 256.
//    Per expert, per 64-wide F-block:
//      GEMM1: A = Xsb (LDS bf16, staged once), B = W1T (GLOBAL bf16 frags)
//      prefetch W2 frags -> regs; GELU*w -> Hsb[pb] (bf16 LDS, dbuf);
//      ONE barrier; GEMM2: A = Hsb[pb], B = w2f regs -> Yacc fp32.
//    Epilogue: register LayerNorm (xor-shuffle over c + 1KB LDS cross-wave).
// ---------------------------------------------------------------------------
__launch_bounds__(256, 4)
__global__ void k_moe_m(const float* __restrict__ xf,
                        const unsigned short* __restrict__ W1T,  // [E][F][D]
                        const unsigned short* __restrict__ W2T,  // [E][D][F]
                        const float* __restrict__ b1,
                        const float* __restrict__ b2,
                        const float* __restrict__ gamma,
                        const float* __restrict__ beta,
                        const float* __restrict__ route,
                        float* __restrict__ out) {
    __shared__ __align__(16) unsigned short Xsb[32][264];     // bf16 X tile
    __shared__ __align__(16) unsigned short Hsb[2][32][72];   // bf16 H, dbuf
    __shared__ float gbuf[256], bbuf[256];
    __shared__ float rred[4][32][2];                          // per-wave LN partials

    const int t = threadIdx.x;
    const int wv = t >> 6;            // wave 0..3
    const int lane = t & 63;
    const int g = lane >> 4;          // quad 0..3
    const int c = lane & 15;          // 0..15
    const int b = blockIdx.x & 7;     // XCD-aligned batch
    const int m0 = (blockIdx.x >> 3) * 32;

    gbuf[t] = gamma[t];
    bbuf[t] = beta[t];

    // ---- stage X tile [32][256] as bf16, once ----
    {
        int row = t >> 3;
        int col0 = (t & 7) * 32;
        const float* src = xf + ((size_t)(b * S_ + m0 + row) * D_ + col0);
        #pragma unroll
        for (int jg = 0; jg < 4; ++jg) {
            float4 a0 = *(const float4*)(src + jg * 8);
            float4 a1 = *(const float4*)(src + jg * 8 + 4);
            float vv[8] = { a0.x, a0.y, a0.z, a0.w, a1.x, a1.y, a1.z, a1.w };
            union { unsigned short u[8]; uint4 q; } o;
            #pragma unroll
            for (int j = 0; j < 8; ++j) o.u[j] = f2bf(vv[j]);
            *(uint4*)&Xsb[row][col0 + jg * 8] = o.q;
        }
    }

    const int e0i = (int)route[b * 4 + 0];
    const int e1i = (int)route[b * 4 + 1];
    const float rw0 = route[b * 4 + 2];
    const float rw1 = route[b * 4 + 3];
    const int eidx[2] = { e0i, e1i };
    const float wgt[2] = { rw0, rw1 };

    f32x4 Yacc[2][4];
    #pragma unroll
    for (int i = 0; i < 2; ++i)
        #pragma unroll
        for (int j = 0; j < 4; ++j)
            #pragma unroll
            for (int r = 0; r < 4; ++r) Yacc[i][j][r] = 0.f;

    __syncthreads();   // Xsb visible to all waves

    int pb = 0;
    for (int sl = 0; sl < 2; ++sl) {
        const int e = eidx[sl];
        const float w = wgt[sl];
        for (int fb = 0; fb < 8; ++fb) {
            // ---- GEMM1: H[32][64] = X @ W1[:, fb*64..]; B from GLOBAL ----
            f32x4 Hacc[2];
            #pragma unroll
            for (int i = 0; i < 2; ++i)
                #pragma unroll
                for (int r = 0; r < 4; ++r) Hacc[i][r] = 0.f;
            const unsigned short* w1p =
                W1T + ((size_t)(e * F_ + fb * 64 + wv * 16 + c)) * D_ + g * 8;
            #pragma unroll
            for (int kc = 0; kc < 8; ++kc) {
                bf16x8 bf = *(const bf16x8*)(w1p + kc * 32);
                bf16x8 a0 = *(const bf16x8*)&Xsb[c][kc * 32 + g * 8];
                bf16x8 a1 = *(const bf16x8*)&Xsb[16 + c][kc * 32 + g * 8];
                Hacc[0] = __builtin_amdgcn_mfma_f32_16x16x32_bf16(a0, bf, Hacc[0], 0, 0, 0);
                Hacc[1] = __builtin_amdgcn_mfma_f32_16x16x32_bf16(a1, bf, Hacc[1], 0, 0, 0);
            }

            // ---- prefetch GEMM2 B-fragments to regs (independent of Hsb) ----
            bf16x8 w2f[2][4];
            {
                const unsigned short* w2p =
                    W2T + ((size_t)(e * D_ + wv * 64 + c)) * F_ + fb * 64 + g * 8;
                #pragma unroll
                for (int kc = 0; kc < 2; ++kc)
                    #pragma unroll
                    for (int nt = 0; nt < 4; ++nt)
                        w2f[kc][nt] = *(const bf16x8*)(w2p + (size_t)(nt * 16) * F_ + kc * 32);
            }

            // ---- GELU(+b1)*w -> Hsb[pb][32][64] (no pre-barrier: dbuf) ----
            {
                float bias1 = b1[e * F_ + fb * 64 + wv * 16 + c];
                #pragma unroll
                for (int mt = 0; mt < 2; ++mt)
                    #pragma unroll
                    for (int r = 0; r < 4; ++r) {
                        int row = mt * 16 + g * 4 + r;
                        float v = Hacc[mt][r] + bias1;
                        float h = 0.5f * v * (1.0f + erff(v * 0.70710678118654752f));
                        Hsb[pb][row][wv * 16 + c] = f2bf(w * h);
                    }
            }
            __syncthreads();   // Hsb[pb] visible (single barrier per fb)

            // ---- GEMM2: Y[32][256] += Hsb[pb] @ w2f ----
            #pragma unroll
            for (int kc = 0; kc < 2; ++kc) {
                bf16x8 a0 = *(const bf16x8*)&Hsb[pb][c][kc * 32 + g * 8];
                bf16x8 a1 = *(const bf16x8*)&Hsb[pb][16 + c][kc * 32 + g * 8];
                #pragma unroll
                for (int nt = 0; nt < 4; ++nt) {
                    Yacc[0][nt] = __builtin_amdgcn_mfma_f32_16x16x32_bf16(a0, w2f[kc][nt], Yacc[0][nt], 0, 0, 0);
                    Yacc[1][nt] = __builtin_amdgcn_mfma_f32_16x16x32_bf16(a1, w2f[kc][nt], Yacc[1][nt], 0, 0, 0);
                }
            }
            pb ^= 1;
        }
    }

    // ---- Epilogue: register LayerNorm (no Yb round-trip) ----
    // Thread holds Y[row][d] for row = mt*16+g*4+r (8 rows),
    // d = wv*64+nt*16+c (4 cols/row).  Row stats: xor-reduce over the 16
    // c-lanes, then cross-wave via rred (1KB LDS), one barrier.
    float bias2[4];
    #pragma unroll
    for (int nt = 0; nt < 4; ++nt) {
        int d = wv * 64 + nt * 16 + c;
        bias2[nt] = rw0 * b2[e0i * D_ + d] + rw1 * b2[e1i * D_ + d];
    }
    #pragma unroll
    for (int mt = 0; mt < 2; ++mt)
        #pragma unroll
        for (int r = 0; r < 4; ++r) {
            int row = mt * 16 + g * 4 + r;
            const float* xr = xf + (size_t)(b * S_ + m0 + row) * D_;
            float s = 0.f, sq = 0.f;
            #pragma unroll
            for (int nt = 0; nt < 4; ++nt) {
                int d = wv * 64 + nt * 16 + c;
                float v = Yacc[mt][nt][r] + bias2[nt] + xr[d];
                Yacc[mt][nt][r] = v;
                s += v; sq += v * v;
            }
            s += __shfl_xor(s, 1); sq += __shfl_xor(sq, 1);
            s += __shfl_xor(s, 2); sq += __shfl_xor(sq, 2);
            s += __shfl_xor(s, 4); sq += __shfl_xor(sq, 4);
            s += __shfl_xor(s, 8); sq += __shfl_xor(sq, 8);
            if (c == 0) { rred[wv][row][0] = s; rred[wv][row][1] = sq; }
        }
    __syncthreads();
    #pragma unroll
    for (int mt = 0; mt < 2; ++mt)
        #pragma unroll
        for (int r = 0; r < 4; ++r) {
            int row = mt * 16 + g * 4 + r;
            float s  = rred[0][row][0] + rred[1][row][0] + rred[2][row][0] + rred[3][row][0];
            float sq = rred[0][row][1] + rred[1][row][1] + rred[2][row][1] + rred[3][row][1];
            float mu = s * (1.0f / 256.0f);
            float var = sq * (1.0f / 256.0f) - mu * mu;
            float rstd = rsqrtf(var + 1e-5f);
            float* op = out + (size_t)(b * S_ + m0 + row) * D_;
            #pragma unroll
            for (int nt = 0; nt < 4; ++nt) {
                int d = wv * 64 + nt * 16 + c;
                op[d] = (Yacc[mt][nt][r] - mu) * rstd * gbuf[d] + bbuf[d];
            }
        }
}

// ---------------------------------------------------------------------------
extern "C" void kernel_launch(void* const* d_in, const int* in_sizes, int n_in,
                              void* d_out, int out_size, void* d_ws, size_t ws_size,
                              hipStream_t stream) {
    const float* x     = (const float*)d_in[0];
    const float* Wr    = (const float*)d_in[1];
    const float* br    = (const float*)d_in[2];
    const float* W1    = (const float*)d_in[3];
    const float* b1    = (const float*)d_in[4];
    const float* W2    = (const float*)d_in[5];
    const float* b2    = (const float*)d_in[6];
    const float* gamma = (const float*)d_in[7];
    const float* beta  = (const float*)d_in[8];
    float* out = (float*)d_out;

    char* ws = (char*)d_ws;
    double* partial = (double*)ws;                               // 1 MB
    float* route  = (float*)(ws + 1064960);                      // 128 B
    unsigned short* W1T = (unsigned short*)(ws + 1081344);       // 2 MB [E][F][D]
    unsigned short* W2T = (unsigned short*)(ws + 3178496);       // 2 MB [E][D][F]
    // total ws usage: ~5.3 MB

    hipLaunchKernelGGL(k_prep, dim3(2560), dim3(256), 0, stream,
                       x, partial, W1, W2, W1T, W2T);
    hipLaunchKernelGGL(k_finish, dim3(1), dim3(256), 0, stream,
                       partial, Wr, br, route);
    hipLaunchKernelGGL(k_moe_m, dim3(1024), dim3(256), 0, stream,
                       x, W1T, W2T, b1, b2, gamma, beta, route, out);
}

// Round 2
// 259.831 us; speedup vs baseline: 1.2081x; 1.1693x over previous
//
#include <hip/hip_runtime.h>
#include <math.h>

// ---------------------------------------------------------------------------
// SparseMoE — MFMA kernel, MI355X (gfx950).  B=8 S=4096 D=256 F=512 E=8 K=2.
// r11 (from r10 @ 303.8us, k_moe_m 147us):
//   * F-block 64 -> 128: barriers per block 19 -> 10; per-phase MFMA doubles;
//     GEMM1 loads amortized over 2 f-subtiles (4 MFMA per 2 ds + 2 global).
//   * erff -> branch-free A&S 7.1.26 erf (|err|<=1.5e-7, negligible vs bf16
//     Hsb quantization). Cuts the dominant VALU term (~128 erff/thread).
//   * W2 kc=0 fragment prefetch pinned with asm keep-alive pre-barrier
//     (r10's prefetch was sunk past the barrier: VGPR_Count=60 proved it).
//   * k_finish: 1024 threads, reduce2 4x parallel; fp64 router across 8
//     threads (1/batch), capacity col-sums computed redundantly. fp64
//     reorder noise ~1e-16, cannot flip top-2 selection.
// Router fp64 deterministic. ws ~5.3 MB.
// ---------------------------------------------------------------------------

#define B_ 8
#define S_ 4096
#define D_ 256
#define F_ 512
#define E_ 8

typedef short bf16x8 __attribute__((ext_vector_type(8)));
typedef float f32x4 __attribute__((ext_vector_type(4)));

static __device__ __forceinline__ unsigned short f2bf(float f) {
    union { float f; unsigned int i; } v; v.f = f;
    unsigned int x = v.i;
    return (unsigned short)((x + 0x7fffu + ((x >> 16) & 1u)) >> 16);  // RNE
}

// GELU(v) = 0.5 v (1 + erf(v/sqrt2)); erf via A&S 7.1.26, |err|<=1.5e-7.
// Branch-free: rcp + 5 fma + hw exp + copysign.
static __device__ __forceinline__ float gelu_f(float v) {
    float x = fabsf(v) * 0.70710678118654752f;
    float t = __builtin_amdgcn_rcpf(1.0f + 0.3275911f * x);
    float p = t * (0.254829592f +
              t * (-0.284496736f +
              t * (1.421413741f +
              t * (-1.453152027f +
              t * 1.061405429f))));
    float er = 1.0f - p * __expf(-x * x);
    er = __builtin_copysignf(er, v);
    return 0.5f * v * (1.0f + er);
}

// ---------------------------------------------------------------------------
// 1) k_prep: fused grid. Blocks [0,512): fp64 partial mean-reduction over S.
//    Blocks [512,1536): W1 [E][256][512] -> W1T [E][512][256] bf16.
//    Blocks [1536,2560): W2 [E][512][256] -> W2T [E][256][512] bf16.
// ---------------------------------------------------------------------------
__global__ void k_prep(const float* __restrict__ x,
                       double* __restrict__ partial,
                       const float* __restrict__ W1,
                       const float* __restrict__ W2,
                       unsigned short* __restrict__ W1T,
                       unsigned short* __restrict__ W2T) {
    int bid = blockIdx.x;
    if (bid < 512) {
        int b = bid >> 6;
        int c = bid & 63;
        int d = threadIdx.x;
        const float* p = x + ((size_t)(b * S_ + c * 64) * D_ + d);
        double acc = 0.0;
        #pragma unroll 8
        for (int i = 0; i < 64; ++i) acc += (double)p[(size_t)i * D_];
        partial[(size_t)bid * D_ + d] = acc;
        return;
    }
    __shared__ float tile[32][33];
    const float* src;
    unsigned short* dst;
    int R, C, cb, rb;
    if (bid < 1536) {
        int b2 = bid - 512;            // e(8) x by(8) x bx(16)
        int e = b2 >> 7, rem = b2 & 127;
        int by = rem >> 4, bx = rem & 15;
        R = 256; C = 512;
        src = W1 + (size_t)e * R * C;
        dst = W1T + (size_t)e * R * C;
        cb = bx * 32; rb = by * 32;
    } else {
        int b2 = bid - 1536;           // e(8) x by(16) x bx(8)
        int e = b2 >> 7, rem = b2 & 127;
        int by = rem >> 3, bx = rem & 7;
        R = 512; C = 256;
        src = W2 + (size_t)e * R * C;
        dst = W2T + (size_t)e * R * C;
        cb = bx * 32; rb = by * 32;
    }
    int tx = threadIdx.x & 31, ty = threadIdx.x >> 5;
    #pragma unroll
    for (int k = 0; k < 4; ++k)
        tile[ty + 8 * k][tx] = src[(size_t)(rb + ty + 8 * k) * C + cb + tx];
    __syncthreads();
    #pragma unroll
    for (int k = 0; k < 4; ++k)
        dst[(size_t)(cb + ty + 8 * k) * R + rb + tx] = f2bf(tile[tx][ty + 8 * k]);
}

// ---------------------------------------------------------------------------
// 2) k_finish: reduce2 (1024 threads, 2 (b,d)-pairs each, per-pair c-order
//    preserved) + fp64 router parallelized over 8 threads (one per batch).
// ---------------------------------------------------------------------------
__global__ void k_finish(const double* __restrict__ partial,
                         const float* __restrict__ Wr,
                         const float* __restrict__ br,
                         float* __restrict__ route) {
    __shared__ double xs[8][256];   // 16 KB
    __shared__ double lg[64];
    __shared__ double rw[8][8];
    int t = threadIdx.x;            // 0..1023
    #pragma unroll
    for (int pp = 0; pp < 2; ++pp) {
        int p = pp * 1024 + t;      // bb = p>>8, d = p&255 (d coalesced)
        int bb = p >> 8, d = p & 255;
        double acc = 0.0;
        #pragma unroll 8
        for (int c = 0; c < 64; ++c)
            acc += partial[(size_t)(bb * 64 + c) * D_ + d];
        xs[bb][d] = acc;
    }
    __syncthreads();
    if (t < 64) {
        int b = t >> 3, e = t & 7;
        double acc = 0.0;
        for (int d = 0; d < D_; ++d)
            acc += (xs[b][d] * (1.0 / (double)S_)) * (double)Wr[d * E_ + e];
        lg[t] = acc + (double)br[e];
    }
    __syncthreads();
    // phase A: first softmax, one thread per batch
    if (t < 8) {
        int bb = t;
        double m = -1e300;
        for (int ee = 0; ee < 8; ++ee) m = fmax(m, lg[bb * 8 + ee]);
        double s = 0.0;
        double p[8];
        for (int ee = 0; ee < 8; ++ee) { p[ee] = exp(lg[bb * 8 + ee] - m); s += p[ee]; }
        for (int ee = 0; ee < 8; ++ee) rw[bb][ee] = p[ee] / s;
    }
    __syncthreads();
    // phase B: capacity scale (col-sums computed redundantly per thread),
    // second softmax, top-2, route write — one thread per batch.
    if (t < 8) {
        int bb = t;
        const double capacity = 5120.0;
        double scale[8];
        for (int ee = 0; ee < 8; ++ee) {
            double load = 0.0;
            for (int b2 = 0; b2 < 8; ++b2) load += rw[b2][ee];
            load *= 4096.0;
            scale[ee] = load > capacity ? capacity / load : 1.0;
        }
        double v[8];
        double m = -1e300;
        for (int ee = 0; ee < 8; ++ee) { v[ee] = rw[bb][ee] * scale[ee]; m = fmax(m, v[ee]); }
        double s = 0.0;
        for (int ee = 0; ee < 8; ++ee) { v[ee] = exp(v[ee] - m); s += v[ee]; }
        for (int ee = 0; ee < 8; ++ee) v[ee] /= s;
        int i1 = 0;
        for (int ee = 1; ee < 8; ++ee) if (v[ee] > v[i1]) i1 = ee;
        int i2 = (i1 == 0) ? 1 : 0;
        for (int ee = 0; ee < 8; ++ee) { if (ee == i1) continue; if (v[ee] > v[i2]) i2 = ee; }
        double d21 = v[i2] - v[i1];
        double ed = exp(d21);
        double w1 = 1.0 / (1.0 + ed);
        double w2 = ed * w1;
        route[bb * 4 + 0] = (float)i1;
        route[bb * 4 + 1] = (float)i2;
        route[bb * 4 + 2] = (float)w1;
        route[bb * 4 + 3] = (float)w2;
    }
}

// ---------------------------------------------------------------------------
// 3) Main MFMA kernel: per block = (batch, 32-token tile). 1024 x 256.
//    Per expert, per 128-wide F-block (4 iters/expert, 8 barriers total):
//      GEMM1: wave wv covers f = fb*128 + wv*32 + {0,16} + c; 32 MFMA.
//      W2 kc=0 frags prefetched + pinned; GELU -> Hsb[pb]; ONE barrier;
//      GEMM2: k=128 (4 kc-chunks), 32 MFMA, kc>0 B-frags load under MFMA.
//    Epilogue: register LayerNorm (xor-shuffle over c + 1KB LDS cross-wave).
// ---------------------------------------------------------------------------
__launch_bounds__(256, 4)
__global__ void k_moe_m(const float* __restrict__ xf,
                        const unsigned short* __restrict__ W1T,  // [E][F][D]
                        const unsigned short* __restrict__ W2T,  // [E][D][F]
                        const float* __restrict__ b1,
                        const float* __restrict__ b2,
                        const float* __restrict__ gamma,
                        const float* __restrict__ beta,
                        const float* __restrict__ route,
                        float* __restrict__ out) {
    __shared__ __align__(16) unsigned short Xsb[32][264];     // bf16 X tile
    __shared__ __align__(16) unsigned short Hsb[2][32][136];  // bf16 H, dbuf
    __shared__ float gbuf[256], bbuf[256];
    __shared__ float rred[4][32][2];                          // LN partials

    const int t = threadIdx.x;
    const int wv = t >> 6;            // wave 0..3
    const int lane = t & 63;
    const int g = lane >> 4;          // quad 0..3
    const int c = lane & 15;          // 0..15
    const int b = blockIdx.x & 7;     // XCD-aligned batch
    const int m0 = (blockIdx.x >> 3) * 32;

    gbuf[t] = gamma[t];
    bbuf[t] = beta[t];

    // ---- stage X tile [32][256] as bf16, once ----
    {
        int row = t >> 3;
        int col0 = (t & 7) * 32;
        const float* src = xf + ((size_t)(b * S_ + m0 + row) * D_ + col0);
        #pragma unroll
        for (int jg = 0; jg < 4; ++jg) {
            float4 a0 = *(const float4*)(src + jg * 8);
            float4 a1 = *(const float4*)(src + jg * 8 + 4);
            float vv[8] = { a0.x, a0.y, a0.z, a0.w, a1.x, a1.y, a1.z, a1.w };
            union { unsigned short u[8]; uint4 q; } o;
            #pragma unroll
            for (int j = 0; j < 8; ++j) o.u[j] = f2bf(vv[j]);
            *(uint4*)&Xsb[row][col0 + jg * 8] = o.q;
        }
    }

    const int e0i = (int)route[b * 4 + 0];
    const int e1i = (int)route[b * 4 + 1];
    const float rw0 = route[b * 4 + 2];
    const float rw1 = route[b * 4 + 3];
    const int eidx[2] = { e0i, e1i };
    const float wgt[2] = { rw0, rw1 };

    f32x4 Yacc[2][4];
    #pragma unroll
    for (int i = 0; i < 2; ++i)
        #pragma unroll
        for (int j = 0; j < 4; ++j)
            #pragma unroll
            for (int r = 0; r < 4; ++r) Yacc[i][j][r] = 0.f;

    __syncthreads();   // Xsb visible to all waves

    int pb = 0;
    for (int sl = 0; sl < 2; ++sl) {
        const int e = eidx[sl];
        const float w = wgt[sl];
        for (int fb = 0; fb < 4; ++fb) {       // 128-wide F blocks
            // ---- GEMM1: H[32][128]; wave covers f = fb*128+wv*32+{0,16}+c
            f32x4 Hacc[2][2];   // [mt][nt2]
            #pragma unroll
            for (int i = 0; i < 2; ++i)
                #pragma unroll
                for (int j = 0; j < 2; ++j)
                    #pragma unroll
                    for (int r = 0; r < 4; ++r) Hacc[i][j][r] = 0.f;
            const unsigned short* w1p =
                W1T + ((size_t)(e * F_ + fb * 128 + wv * 32 + c)) * D_ + g * 8;
            #pragma unroll
            for (int kc = 0; kc < 8; ++kc) {
                bf16x8 a0 = *(const bf16x8*)&Xsb[c][kc * 32 + g * 8];
                bf16x8 a1 = *(const bf16x8*)&Xsb[16 + c][kc * 32 + g * 8];
                bf16x8 b0 = *(const bf16x8*)(w1p + kc * 32);
                bf16x8 b1v = *(const bf16x8*)(w1p + (size_t)16 * D_ + kc * 32);
                Hacc[0][0] = __builtin_amdgcn_mfma_f32_16x16x32_bf16(a0, b0, Hacc[0][0], 0, 0, 0);
                Hacc[1][0] = __builtin_amdgcn_mfma_f32_16x16x32_bf16(a1, b0, Hacc[1][0], 0, 0, 0);
                Hacc[0][1] = __builtin_amdgcn_mfma_f32_16x16x32_bf16(a0, b1v, Hacc[0][1], 0, 0, 0);
                Hacc[1][1] = __builtin_amdgcn_mfma_f32_16x16x32_bf16(a1, b1v, Hacc[1][1], 0, 0, 0);
            }

            // ---- prefetch GEMM2 kc=0 B-frags; pin so they can't sink ----
            const unsigned short* w2p =
                W2T + ((size_t)(e * D_ + wv * 64 + c)) * F_ + fb * 128 + g * 8;
            bf16x8 w2f0[4];
            #pragma unroll
            for (int nt = 0; nt < 4; ++nt)
                w2f0[nt] = *(const bf16x8*)(w2p + (size_t)(nt * 16) * F_);

            // ---- GELU(+b1)*w -> Hsb[pb][32][128] (dbuf, no pre-barrier) ----
            #pragma unroll
            for (int nt2 = 0; nt2 < 2; ++nt2) {
                float bias1 = b1[e * F_ + fb * 128 + wv * 32 + nt2 * 16 + c];
                #pragma unroll
                for (int mt = 0; mt < 2; ++mt)
                    #pragma unroll
                    for (int r = 0; r < 4; ++r) {
                        int row = mt * 16 + g * 4 + r;
                        float v = Hacc[mt][nt2][r] + bias1;
                        Hsb[pb][row][wv * 32 + nt2 * 16 + c] = f2bf(w * gelu_f(v));
                    }
            }
            asm volatile("" : "+v"(w2f0[0]), "+v"(w2f0[1]), "+v"(w2f0[2]), "+v"(w2f0[3]));
            __syncthreads();   // Hsb[pb] visible (single barrier per fb)

            // ---- GEMM2: Y[32][256] += Hsb[pb] @ W2[fb*128..][:] ----
            #pragma unroll
            for (int kc = 0; kc < 4; ++kc) {
                bf16x8 a0 = *(const bf16x8*)&Hsb[pb][c][kc * 32 + g * 8];
                bf16x8 a1 = *(const bf16x8*)&Hsb[pb][16 + c][kc * 32 + g * 8];
                #pragma unroll
                for (int nt = 0; nt < 4; ++nt) {
                    bf16x8 bf = (kc == 0) ? w2f0[nt]
                        : *(const bf16x8*)(w2p + (size_t)(nt * 16) * F_ + kc * 32);
                    Yacc[0][nt] = __builtin_amdgcn_mfma_f32_16x16x32_bf16(a0, bf, Yacc[0][nt], 0, 0, 0);
                    Yacc[1][nt] = __builtin_amdgcn_mfma_f32_16x16x32_bf16(a1, bf, Yacc[1][nt], 0, 0, 0);
                }
            }
            pb ^= 1;
        }
    }

    // ---- Epilogue: register LayerNorm (no LDS Y round-trip) ----
    float bias2[4];
    #pragma unroll
    for (int nt = 0; nt < 4; ++nt) {
        int d = wv * 64 + nt * 16 + c;
        bias2[nt] = rw0 * b2[e0i * D_ + d] + rw1 * b2[e1i * D_ + d];
    }
    #pragma unroll
    for (int mt = 0; mt < 2; ++mt)
        #pragma unroll
        for (int r = 0; r < 4; ++r) {
            int row = mt * 16 + g * 4 + r;
            const float* xr = xf + (size_t)(b * S_ + m0 + row) * D_;
            float s = 0.f, sq = 0.f;
            #pragma unroll
            for (int nt = 0; nt < 4; ++nt) {
                int d = wv * 64 + nt * 16 + c;
                float v = Yacc[mt][nt][r] + bias2[nt] + xr[d];
                Yacc[mt][nt][r] = v;
                s += v; sq += v * v;
            }
            s += __shfl_xor(s, 1); sq += __shfl_xor(sq, 1);
            s += __shfl_xor(s, 2); sq += __shfl_xor(sq, 2);
            s += __shfl_xor(s, 4); sq += __shfl_xor(sq, 4);
            s += __shfl_xor(s, 8); sq += __shfl_xor(sq, 8);
            if (c == 0) { rred[wv][row][0] = s; rred[wv][row][1] = sq; }
        }
    __syncthreads();
    #pragma unroll
    for (int mt = 0; mt < 2; ++mt)
        #pragma unroll
        for (int r = 0; r < 4; ++r) {
            int row = mt * 16 + g * 4 + r;
            float s  = rred[0][row][0] + rred[1][row][0] + rred[2][row][0] + rred[3][row][0];
            float sq = rred[0][row][1] + rred[1][row][1] + rred[2][row][1] + rred[3][row][1];
            float mu = s * (1.0f / 256.0f);
            float var = sq * (1.0f / 256.0f) - mu * mu;
            float rstd = rsqrtf(var + 1e-5f);
            float* op = out + (size_t)(b * S_ + m0 + row) * D_;
            #pragma unroll
            for (int nt = 0; nt < 4; ++nt) {
                int d = wv * 64 + nt * 16 + c;
                op[d] = (Yacc[mt][nt][r] - mu) * rstd * gbuf[d] + bbuf[d];
            }
        }
}

// ---------------------------------------------------------------------------
extern "C" void kernel_launch(void* const* d_in, const int* in_sizes, int n_in,
                              void* d_out, int out_size, void* d_ws, size_t ws_size,
                              hipStream_t stream) {
    const float* x     = (const float*)d_in[0];
    const float* Wr    = (const float*)d_in[1];
    const float* br    = (const float*)d_in[2];
    const float* W1    = (const float*)d_in[3];
    const float* b1    = (const float*)d_in[4];
    const float* W2    = (const float*)d_in[5];
    const float* b2    = (const float*)d_in[6];
    const float* gamma = (const float*)d_in[7];
    const float* beta  = (const float*)d_in[8];
    float* out = (float*)d_out;

    char* ws = (char*)d_ws;
    double* partial = (double*)ws;                               // 1 MB
    float* route  = (float*)(ws + 1064960);                      // 128 B
    unsigned short* W1T = (unsigned short*)(ws + 1081344);       // 2 MB [E][F][D]
    unsigned short* W2T = (unsigned short*)(ws + 3178496);       // 2 MB [E][D][F]
    // total ws usage: ~5.3 MB

    hipLaunchKernelGGL(k_prep, dim3(2560), dim3(256), 0, stream,
                       x, partial, W1, W2, W1T, W2T);
    hipLaunchKernelGGL(k_finish, dim3(1), dim3(1024), 0, stream,
                       partial, Wr, br, route);
    hipLaunchKernelGGL(k_moe_m, dim3(1024), dim3(256), 0, stream,
                       x, W1T, W2T, b1, b2, gamma, beta, route, out);
}

// Round 3
// 222.100 us; speedup vs baseline: 1.4133x; 1.1699x over previous
//
#include <hip/hip_runtime.h>
#include <math.h>

// ---------------------------------------------------------------------------
// SparseMoE — MFMA kernel, MI355X (gfx950).  B=8 S=4096 D=256 F=512 E=8 K=2.
// r12 (from r11 @ 259.8us, k_moe_m 138.5us, MfmaUtil 9.6, VGPR 52):
//   * M=64 tokens/block, 8 waves, 512 blocks: each B-frag feeds 4 MFMAs
//     (was 2); W-panel L2 traffic halves (512MB).
//   * All 16 B-frags (w1f[8], w2f[4][2]) batch-issued into register arrays
//     at iteration start + asm-pinned: ONE L2 latency window per iteration.
//     (r11's VGPR_Count=52 proved the compiler was sinking loads to uses,
//     leaving ~1-2 loads in flight per wave = the 70% idle-issue stall.)
//   * __syncthreads -> s_waitcnt lgkmcnt(0) + raw s_barrier (LDS is the only
//     cross-wave medium): global loads survive barriers, no vmcnt(0) drain.
// MFMA accumulation order per output unchanged -> absmax unchanged.
// Router fp64 deterministic. ws ~5.3 MB.
// ---------------------------------------------------------------------------

#define B_ 8
#define S_ 4096
#define D_ 256
#define F_ 512
#define E_ 8

typedef short bf16x8 __attribute__((ext_vector_type(8)));
typedef float f32x4 __attribute__((ext_vector_type(4)));

static __device__ __forceinline__ unsigned short f2bf(float f) {
    union { float f; unsigned int i; } v; v.f = f;
    unsigned int x = v.i;
    return (unsigned short)((x + 0x7fffu + ((x >> 16) & 1u)) >> 16);  // RNE
}

// barrier that drains LDS ops only — global loads stay in flight
static __device__ __forceinline__ void bar_lds() {
    asm volatile("s_waitcnt lgkmcnt(0)" ::: "memory");
    __builtin_amdgcn_s_barrier();
}

// GELU(v) = 0.5 v (1 + erf(v/sqrt2)); erf via A&S 7.1.26, |err|<=1.5e-7.
static __device__ __forceinline__ float gelu_f(float v) {
    float x = fabsf(v) * 0.70710678118654752f;
    float t = __builtin_amdgcn_rcpf(1.0f + 0.3275911f * x);
    float p = t * (0.254829592f +
              t * (-0.284496736f +
              t * (1.421413741f +
              t * (-1.453152027f +
              t * 1.061405429f))));
    float er = 1.0f - p * __expf(-x * x);
    er = __builtin_copysignf(er, v);
    return 0.5f * v * (1.0f + er);
}

// ---------------------------------------------------------------------------
// 1) k_prep: fused grid. Blocks [0,512): fp64 partial mean-reduction over S.
//    Blocks [512,1536): W1 [E][256][512] -> W1T [E][512][256] bf16.
//    Blocks [1536,2560): W2 [E][512][256] -> W2T [E][256][512] bf16.
// ---------------------------------------------------------------------------
__global__ void k_prep(const float* __restrict__ x,
                       double* __restrict__ partial,
                       const float* __restrict__ W1,
                       const float* __restrict__ W2,
                       unsigned short* __restrict__ W1T,
                       unsigned short* __restrict__ W2T) {
    int bid = blockIdx.x;
    if (bid < 512) {
        int b = bid >> 6;
        int c = bid & 63;
        int d = threadIdx.x;
        const float* p = x + ((size_t)(b * S_ + c * 64) * D_ + d);
        double acc = 0.0;
        #pragma unroll 8
        for (int i = 0; i < 64; ++i) acc += (double)p[(size_t)i * D_];
        partial[(size_t)bid * D_ + d] = acc;
        return;
    }
    __shared__ float tile[32][33];
    const float* src;
    unsigned short* dst;
    int R, C, cb, rb;
    if (bid < 1536) {
        int b2 = bid - 512;            // e(8) x by(8) x bx(16)
        int e = b2 >> 7, rem = b2 & 127;
        int by = rem >> 4, bx = rem & 15;
        R = 256; C = 512;
        src = W1 + (size_t)e * R * C;
        dst = W1T + (size_t)e * R * C;
        cb = bx * 32; rb = by * 32;
    } else {
        int b2 = bid - 1536;           // e(8) x by(16) x bx(8)
        int e = b2 >> 7, rem = b2 & 127;
        int by = rem >> 3, bx = rem & 7;
        R = 512; C = 256;
        src = W2 + (size_t)e * R * C;
        dst = W2T + (size_t)e * R * C;
        cb = bx * 32; rb = by * 32;
    }
    int tx = threadIdx.x & 31, ty = threadIdx.x >> 5;
    #pragma unroll
    for (int k = 0; k < 4; ++k)
        tile[ty + 8 * k][tx] = src[(size_t)(rb + ty + 8 * k) * C + cb + tx];
    __syncthreads();
    #pragma unroll
    for (int k = 0; k < 4; ++k)
        dst[(size_t)(cb + ty + 8 * k) * R + rb + tx] = f2bf(tile[tx][ty + 8 * k]);
}

// ---------------------------------------------------------------------------
// 2) k_finish: reduce2 (1024 threads) + fp64 router over 8 threads.
// ---------------------------------------------------------------------------
__global__ void k_finish(const double* __restrict__ partial,
                         const float* __restrict__ Wr,
                         const float* __restrict__ br,
                         float* __restrict__ route) {
    __shared__ double xs[8][256];   // 16 KB
    __shared__ double lg[64];
    __shared__ double rw[8][8];
    int t = threadIdx.x;            // 0..1023
    #pragma unroll
    for (int pp = 0; pp < 2; ++pp) {
        int p = pp * 1024 + t;      // bb = p>>8, d = p&255 (d coalesced)
        int bb = p >> 8, d = p & 255;
        double acc = 0.0;
        #pragma unroll 8
        for (int c = 0; c < 64; ++c)
            acc += partial[(size_t)(bb * 64 + c) * D_ + d];
        xs[bb][d] = acc;
    }
    __syncthreads();
    if (t < 64) {
        int b = t >> 3, e = t & 7;
        double acc = 0.0;
        for (int d = 0; d < D_; ++d)
            acc += (xs[b][d] * (1.0 / (double)S_)) * (double)Wr[d * E_ + e];
        lg[t] = acc + (double)br[e];
    }
    __syncthreads();
    if (t < 8) {
        int bb = t;
        double m = -1e300;
        for (int ee = 0; ee < 8; ++ee) m = fmax(m, lg[bb * 8 + ee]);
        double s = 0.0;
        double p[8];
        for (int ee = 0; ee < 8; ++ee) { p[ee] = exp(lg[bb * 8 + ee] - m); s += p[ee]; }
        for (int ee = 0; ee < 8; ++ee) rw[bb][ee] = p[ee] / s;
    }
    __syncthreads();
    if (t < 8) {
        int bb = t;
        const double capacity = 5120.0;
        double scale[8];
        for (int ee = 0; ee < 8; ++ee) {
            double load = 0.0;
            for (int b2 = 0; b2 < 8; ++b2) load += rw[b2][ee];
            load *= 4096.0;
            scale[ee] = load > capacity ? capacity / load : 1.0;
        }
        double v[8];
        double m = -1e300;
        for (int ee = 0; ee < 8; ++ee) { v[ee] = rw[bb][ee] * scale[ee]; m = fmax(m, v[ee]); }
        double s = 0.0;
        for (int ee = 0; ee < 8; ++ee) { v[ee] = exp(v[ee] - m); s += v[ee]; }
        for (int ee = 0; ee < 8; ++ee) v[ee] /= s;
        int i1 = 0;
        for (int ee = 1; ee < 8; ++ee) if (v[ee] > v[i1]) i1 = ee;
        int i2 = (i1 == 0) ? 1 : 0;
        for (int ee = 0; ee < 8; ++ee) { if (ee == i1) continue; if (v[ee] > v[i2]) i2 = ee; }
        double d21 = v[i2] - v[i1];
        double ed = exp(d21);
        double w1 = 1.0 / (1.0 + ed);
        double w2 = ed * w1;
        route[bb * 4 + 0] = (float)i1;
        route[bb * 4 + 1] = (float)i2;
        route[bb * 4 + 2] = (float)w1;
        route[bb * 4 + 3] = (float)w2;
    }
}

// ---------------------------------------------------------------------------
// 3) Main MFMA kernel: per block = (batch, 64-token tile). 512 x 512 thr.
//    8 waves; wave wv covers f-cols wv*16+c (GEMM1) / d-cols wv*32+nt*16+c
//    (GEMM2); 4 m-tiles per wave -> 4 MFMAs per B-fragment.
//    Per expert, per 128-wide F-block: batch-issue w1f[8]+w2f[8] -> pin ->
//    GEMM1 -> GELU -> pin w2f -> lgkm-barrier -> GEMM2.
// ---------------------------------------------------------------------------
__launch_bounds__(512, 4)
__global__ void k_moe_m(const float* __restrict__ xf,
                        const unsigned short* __restrict__ W1T,  // [E][F][D]
                        const unsigned short* __restrict__ W2T,  // [E][D][F]
                        const float* __restrict__ b1,
                        const float* __restrict__ b2,
                        const float* __restrict__ gamma,
                        const float* __restrict__ beta,
                        const float* __restrict__ route,
                        float* __restrict__ out) {
    __shared__ __align__(16) unsigned short Xsb[64][264];     // 33.8 KB
    __shared__ __align__(16) unsigned short Hsb[2][64][136];  // 34.8 KB dbuf
    __shared__ float gbuf[256], bbuf[256];
    __shared__ __align__(16) float rred[64][20];              // LN partials

    const int t = threadIdx.x;        // 0..511
    const int wv = t >> 6;            // wave 0..7
    const int lane = t & 63;
    const int g = lane >> 4;          // quad 0..3
    const int c = lane & 15;          // 0..15
    const int b = blockIdx.x & 7;     // XCD-aligned batch
    const int m0 = (blockIdx.x >> 3) * 64;

    if (t < 256) { gbuf[t] = gamma[t]; bbuf[t] = beta[t]; }

    // ---- stage X tile [64][256] as bf16, once ----
    {
        int row = t >> 3;
        int col0 = (t & 7) * 32;
        const float* src = xf + ((size_t)(b * S_ + m0 + row) * D_ + col0);
        #pragma unroll
        for (int jg = 0; jg < 4; ++jg) {
            float4 a0 = *(const float4*)(src + jg * 8);
            float4 a1 = *(const float4*)(src + jg * 8 + 4);
            float vv[8] = { a0.x, a0.y, a0.z, a0.w, a1.x, a1.y, a1.z, a1.w };
            union { unsigned short u[8]; uint4 q; } o;
            #pragma unroll
            for (int j = 0; j < 8; ++j) o.u[j] = f2bf(vv[j]);
            *(uint4*)&Xsb[row][col0 + jg * 8] = o.q;
        }
    }

    const int e0i = (int)route[b * 4 + 0];
    const int e1i = (int)route[b * 4 + 1];
    const float rw0 = route[b * 4 + 2];
    const float rw1 = route[b * 4 + 3];
    const int eidx[2] = { e0i, e1i };
    const float wgt[2] = { rw0, rw1 };

    f32x4 Yacc[4][2];
    #pragma unroll
    for (int i = 0; i < 4; ++i)
        #pragma unroll
        for (int j = 0; j < 2; ++j)
            #pragma unroll
            for (int r = 0; r < 4; ++r) Yacc[i][j][r] = 0.f;

    bar_lds();   // Xsb visible to all waves

    int pb = 0;
    for (int sl = 0; sl < 2; ++sl) {
        const int e = eidx[sl];
        const float w = wgt[sl];
        for (int fb = 0; fb < 4; ++fb) {       // 128-wide F blocks
            // ---- batch-issue ALL B-fragment loads for this iteration ----
            const unsigned short* w1p =
                W1T + ((size_t)(e * F_ + fb * 128 + wv * 16 + c)) * D_ + g * 8;
            bf16x8 w1f[8];
            #pragma unroll
            for (int kc = 0; kc < 8; ++kc)
                w1f[kc] = *(const bf16x8*)(w1p + kc * 32);
            const unsigned short* w2p =
                W2T + ((size_t)(e * D_ + wv * 32 + c)) * F_ + fb * 128 + g * 8;
            bf16x8 w2f[4][2];
            #pragma unroll
            for (int kc = 0; kc < 4; ++kc)
                #pragma unroll
                for (int nt = 0; nt < 2; ++nt)
                    w2f[kc][nt] = *(const bf16x8*)(w2p + (size_t)(nt * 16) * F_ + kc * 32);
            // pin w1f: forces the batch issue to stick (waits only w1f's 8)
            asm volatile("" : "+v"(w1f[0]), "+v"(w1f[1]), "+v"(w1f[2]), "+v"(w1f[3]),
                              "+v"(w1f[4]), "+v"(w1f[5]), "+v"(w1f[6]), "+v"(w1f[7]));

            // ---- GEMM1: H[64][128]; wave covers f = fb*128 + wv*16 + c ----
            f32x4 Hacc[4];
            #pragma unroll
            for (int i = 0; i < 4; ++i)
                #pragma unroll
                for (int r = 0; r < 4; ++r) Hacc[i][r] = 0.f;
            #pragma unroll
            for (int kc = 0; kc < 8; ++kc) {
                #pragma unroll
                for (int mt = 0; mt < 4; ++mt) {
                    bf16x8 a = *(const bf16x8*)&Xsb[mt * 16 + c][kc * 32 + g * 8];
                    Hacc[mt] = __builtin_amdgcn_mfma_f32_16x16x32_bf16(a, w1f[kc], Hacc[mt], 0, 0, 0);
                }
            }

            // ---- GELU(+b1)*w -> Hsb[pb][64][128] (dbuf, no pre-barrier) ----
            {
                float bias1 = b1[e * F_ + fb * 128 + wv * 16 + c];
                #pragma unroll
                for (int mt = 0; mt < 4; ++mt)
                    #pragma unroll
                    for (int r = 0; r < 4; ++r) {
                        int row = mt * 16 + g * 4 + r;
                        float v = Hacc[mt][r] + bias1;
                        Hsb[pb][row][wv * 16 + c] = f2bf(w * gelu_f(v));
                    }
            }
            // pin w2f (loads long since arrived; prevents sinking past barrier)
            asm volatile("" : "+v"(w2f[0][0]), "+v"(w2f[0][1]), "+v"(w2f[1][0]), "+v"(w2f[1][1]),
                              "+v"(w2f[2][0]), "+v"(w2f[2][1]), "+v"(w2f[3][0]), "+v"(w2f[3][1]));
            bar_lds();   // Hsb[pb] visible; global loads stay in flight

            // ---- GEMM2: Y[64][256] += Hsb[pb] @ w2f ----
            #pragma unroll
            for (int kc = 0; kc < 4; ++kc) {
                #pragma unroll
                for (int mt = 0; mt < 4; ++mt) {
                    bf16x8 a = *(const bf16x8*)&Hsb[pb][mt * 16 + c][kc * 32 + g * 8];
                    #pragma unroll
                    for (int nt = 0; nt < 2; ++nt)
                        Yacc[mt][nt] = __builtin_amdgcn_mfma_f32_16x16x32_bf16(a, w2f[kc][nt], Yacc[mt][nt], 0, 0, 0);
                }
            }
            pb ^= 1;
        }
    }

    // ---- Epilogue: register LayerNorm ----
    // lane holds Y[row][d]: row = mt*16+g*4+r (16 rows), d = wv*32+nt*16+c.
    float bias2[2];
    #pragma unroll
    for (int nt = 0; nt < 2; ++nt) {
        int d = wv * 32 + nt * 16 + c;
        bias2[nt] = rw0 * b2[e0i * D_ + d] + rw1 * b2[e1i * D_ + d];
    }
    #pragma unroll
    for (int mt = 0; mt < 4; ++mt)
        #pragma unroll
        for (int r = 0; r < 4; ++r) {
            int row = mt * 16 + g * 4 + r;
            const float* xr = xf + (size_t)(b * S_ + m0 + row) * D_;
            float s = 0.f, sq = 0.f;
            #pragma unroll
            for (int nt = 0; nt < 2; ++nt) {
                int d = wv * 32 + nt * 16 + c;
                float v = Yacc[mt][nt][r] + bias2[nt] + xr[d];
                Yacc[mt][nt][r] = v;
                s += v; sq += v * v;
            }
            s += __shfl_xor(s, 1); sq += __shfl_xor(sq, 1);
            s += __shfl_xor(s, 2); sq += __shfl_xor(sq, 2);
            s += __shfl_xor(s, 4); sq += __shfl_xor(sq, 4);
            s += __shfl_xor(s, 8); sq += __shfl_xor(sq, 8);
            if (c == 0) { rred[row][wv * 2] = s; rred[row][wv * 2 + 1] = sq; }
        }
    bar_lds();
    #pragma unroll
    for (int mt = 0; mt < 4; ++mt)
        #pragma unroll
        for (int r = 0; r < 4; ++r) {
            int row = mt * 16 + g * 4 + r;
            float4 p0 = *(const float4*)&rred[row][0];
            float4 p1 = *(const float4*)&rred[row][4];
            float4 p2 = *(const float4*)&rred[row][8];
            float4 p3 = *(const float4*)&rred[row][12];
            float s  = ((p0.x + p1.x) + (p2.x + p3.x)) + ((p0.z + p1.z) + (p2.z + p3.z));
            float sq = ((p0.y + p1.y) + (p2.y + p3.y)) + ((p0.w + p1.w) + (p2.w + p3.w));
            float mu = s * (1.0f / 256.0f);
            float var = sq * (1.0f / 256.0f) - mu * mu;
            float rstd = rsqrtf(var + 1e-5f);
            float* op = out + (size_t)(b * S_ + m0 + row) * D_;
            #pragma unroll
            for (int nt = 0; nt < 2; ++nt) {
                int d = wv * 32 + nt * 16 + c;
                op[d] = (Yacc[mt][nt][r] - mu) * rstd * gbuf[d] + bbuf[d];
            }
        }
}

// ---------------------------------------------------------------------------
extern "C" void kernel_launch(void* const* d_in, const int* in_sizes, int n_in,
                              void* d_out, int out_size, void* d_ws, size_t ws_size,
                              hipStream_t stream) {
    const float* x     = (const float*)d_in[0];
    const float* Wr    = (const float*)d_in[1];
    const float* br    = (const float*)d_in[2];
    const float* W1    = (const float*)d_in[3];
    const float* b1    = (const float*)d_in[4];
    const float* W2    = (const float*)d_in[5];
    const float* b2    = (const float*)d_in[6];
    const float* gamma = (const float*)d_in[7];
    const float* beta  = (const float*)d_in[8];
    float* out = (float*)d_out;

    char* ws = (char*)d_ws;
    double* partial = (double*)ws;                               // 1 MB
    float* route  = (float*)(ws + 1064960);                      // 128 B
    unsigned short* W1T = (unsigned short*)(ws + 1081344);       // 2 MB [E][F][D]
    unsigned short* W2T = (unsigned short*)(ws + 3178496);       // 2 MB [E][D][F]
    // total ws usage: ~5.3 MB

    hipLaunchKernelGGL(k_prep, dim3(2560), dim3(256), 0, stream,
                       x, partial, W1, W2, W1T, W2T);
    hipLaunchKernelGGL(k_finish, dim3(1), dim3(1024), 0, stream,
                       partial, Wr, br, route);
    hipLaunchKernelGGL(k_moe_m, dim3(512), dim3(512), 0, stream,
                       x, W1T, W2T, b1, b2, gamma, beta, route, out);
}

// Round 4
// 213.450 us; speedup vs baseline: 1.4706x; 1.0405x over previous
//
#include <hip/hip_runtime.h>
#include <math.h>

// ---------------------------------------------------------------------------
// SparseMoE — MFMA kernel, MI355X (gfx950).  B=8 S=4096 D=256 F=512 E=8 K=2.
// r13 (from r12 @ 222.1us, k_moe_m 104.4us, MfmaUtil 13.1, VGPR 64):
//   * Register-neutral software pipeline of the W stream:
//       - w2f_i issued at iteration TOP (first use: GEMM2, ~1200cyc later).
//       - w1f_{i+1} issued post-GELU, pre-barrier (first use: next GEMM1).
//       Old w1f dies at GEMM1, new w1f lives post-GELU -> same 32 regs.
//   * asm value-pins REMOVED: a "+v" pin is a USE and forces s_waitcnt at
//     the pin (r12 stalled a full delivery window per iteration). bar_lds's
//     "memory" clobber pins load-issue placement without draining vmcnt;
//     in-flight loads span the barrier.
//   * f2bf -> v_cvt_pk_bf16_f32 (RNE, bit-identical for finite values) in
//     X staging and GELU->Hsb stores: big VALU trim on the busiest pipe.
// Router fp64 deterministic. ws ~5.3 MB.
// ---------------------------------------------------------------------------

#define B_ 8
#define S_ 4096
#define D_ 256
#define F_ 512
#define E_ 8

typedef short bf16x8 __attribute__((ext_vector_type(8)));
typedef float f32x4 __attribute__((ext_vector_type(4)));

static __device__ __forceinline__ unsigned short f2bf(float f) {
    union { float f; unsigned int i; } v; v.f = f;
    unsigned int x = v.i;
    return (unsigned short)((x + 0x7fffu + ((x >> 16) & 1u)) >> 16);  // RNE
}

// pack two f32 -> two bf16 (RNE), lo = s0, hi = s1
static __device__ __forceinline__ unsigned int cvt_pk_bf16(float s0, float s1) {
    unsigned int r;
    asm("v_cvt_pk_bf16_f32 %0, %1, %2" : "=v"(r) : "v"(s0), "v"(s1));
    return r;
}

// barrier that drains LDS ops only — global loads stay in flight.
// The "memory" clobber also pins global-load issue placement (no motion
// across the barrier in either direction).
static __device__ __forceinline__ void bar_lds() {
    asm volatile("s_waitcnt lgkmcnt(0)" ::: "memory");
    __builtin_amdgcn_s_barrier();
}

// GELU(v) = 0.5 v (1 + erf(v/sqrt2)); erf via A&S 7.1.26, |err|<=1.5e-7.
static __device__ __forceinline__ float gelu_f(float v) {
    float x = fabsf(v) * 0.70710678118654752f;
    float t = __builtin_amdgcn_rcpf(1.0f + 0.3275911f * x);
    float p = t * (0.254829592f +
              t * (-0.284496736f +
              t * (1.421413741f +
              t * (-1.453152027f +
              t * 1.061405429f))));
    float er = 1.0f - p * __expf(-x * x);
    er = __builtin_copysignf(er, v);
    return 0.5f * v * (1.0f + er);
}

// ---------------------------------------------------------------------------
// 1) k_prep: fused grid. Blocks [0,512): fp64 partial mean-reduction over S.
//    Blocks [512,1536): W1 [E][256][512] -> W1T [E][512][256] bf16.
//    Blocks [1536,2560): W2 [E][512][256] -> W2T [E][256][512] bf16.
// ---------------------------------------------------------------------------
__global__ void k_prep(const float* __restrict__ x,
                       double* __restrict__ partial,
                       const float* __restrict__ W1,
                       const float* __restrict__ W2,
                       unsigned short* __restrict__ W1T,
                       unsigned short* __restrict__ W2T) {
    int bid = blockIdx.x;
    if (bid < 512) {
        int b = bid >> 6;
        int c = bid & 63;
        int d = threadIdx.x;
        const float* p = x + ((size_t)(b * S_ + c * 64) * D_ + d);
        double acc = 0.0;
        #pragma unroll 8
        for (int i = 0; i < 64; ++i) acc += (double)p[(size_t)i * D_];
        partial[(size_t)bid * D_ + d] = acc;
        return;
    }
    __shared__ float tile[32][33];
    const float* src;
    unsigned short* dst;
    int R, C, cb, rb;
    if (bid < 1536) {
        int b2 = bid - 512;            // e(8) x by(8) x bx(16)
        int e = b2 >> 7, rem = b2 & 127;
        int by = rem >> 4, bx = rem & 15;
        R = 256; C = 512;
        src = W1 + (size_t)e * R * C;
        dst = W1T + (size_t)e * R * C;
        cb = bx * 32; rb = by * 32;
    } else {
        int b2 = bid - 1536;           // e(8) x by(16) x bx(8)
        int e = b2 >> 7, rem = b2 & 127;
        int by = rem >> 3, bx = rem & 7;
        R = 512; C = 256;
        src = W2 + (size_t)e * R * C;
        dst = W2T + (size_t)e * R * C;
        cb = bx * 32; rb = by * 32;
    }
    int tx = threadIdx.x & 31, ty = threadIdx.x >> 5;
    #pragma unroll
    for (int k = 0; k < 4; ++k)
        tile[ty + 8 * k][tx] = src[(size_t)(rb + ty + 8 * k) * C + cb + tx];
    __syncthreads();
    #pragma unroll
    for (int k = 0; k < 4; ++k)
        dst[(size_t)(cb + ty + 8 * k) * R + rb + tx] = f2bf(tile[tx][ty + 8 * k]);
}

// ---------------------------------------------------------------------------
// 2) k_finish: reduce2 (1024 threads) + fp64 router over 8 threads.
// ---------------------------------------------------------------------------
__global__ void k_finish(const double* __restrict__ partial,
                         const float* __restrict__ Wr,
                         const float* __restrict__ br,
                         float* __restrict__ route) {
    __shared__ double xs[8][256];   // 16 KB
    __shared__ double lg[64];
    __shared__ double rw[8][8];
    int t = threadIdx.x;            // 0..1023
    #pragma unroll
    for (int pp = 0; pp < 2; ++pp) {
        int p = pp * 1024 + t;      // bb = p>>8, d = p&255 (d coalesced)
        int bb = p >> 8, d = p & 255;
        double acc = 0.0;
        #pragma unroll 8
        for (int c = 0; c < 64; ++c)
            acc += partial[(size_t)(bb * 64 + c) * D_ + d];
        xs[bb][d] = acc;
    }
    __syncthreads();
    if (t < 64) {
        int b = t >> 3, e = t & 7;
        double acc = 0.0;
        for (int d = 0; d < D_; ++d)
            acc += (xs[b][d] * (1.0 / (double)S_)) * (double)Wr[d * E_ + e];
        lg[t] = acc + (double)br[e];
    }
    __syncthreads();
    if (t < 8) {
        int bb = t;
        double m = -1e300;
        for (int ee = 0; ee < 8; ++ee) m = fmax(m, lg[bb * 8 + ee]);
        double s = 0.0;
        double p[8];
        for (int ee = 0; ee < 8; ++ee) { p[ee] = exp(lg[bb * 8 + ee] - m); s += p[ee]; }
        for (int ee = 0; ee < 8; ++ee) rw[bb][ee] = p[ee] / s;
    }
    __syncthreads();
    if (t < 8) {
        int bb = t;
        const double capacity = 5120.0;
        double scale[8];
        for (int ee = 0; ee < 8; ++ee) {
            double load = 0.0;
            for (int b2 = 0; b2 < 8; ++b2) load += rw[b2][ee];
            load *= 4096.0;
            scale[ee] = load > capacity ? capacity / load : 1.0;
        }
        double v[8];
        double m = -1e300;
        for (int ee = 0; ee < 8; ++ee) { v[ee] = rw[bb][ee] * scale[ee]; m = fmax(m, v[ee]); }
        double s = 0.0;
        for (int ee = 0; ee < 8; ++ee) { v[ee] = exp(v[ee] - m); s += v[ee]; }
        for (int ee = 0; ee < 8; ++ee) v[ee] /= s;
        int i1 = 0;
        for (int ee = 1; ee < 8; ++ee) if (v[ee] > v[i1]) i1 = ee;
        int i2 = (i1 == 0) ? 1 : 0;
        for (int ee = 0; ee < 8; ++ee) { if (ee == i1) continue; if (v[ee] > v[i2]) i2 = ee; }
        double d21 = v[i2] - v[i1];
        double ed = exp(d21);
        double w1 = 1.0 / (1.0 + ed);
        double w2 = ed * w1;
        route[bb * 4 + 0] = (float)i1;
        route[bb * 4 + 1] = (float)i2;
        route[bb * 4 + 2] = (float)w1;
        route[bb * 4 + 3] = (float)w2;
    }
}

// ---------------------------------------------------------------------------
// 3) Main MFMA kernel: per block = (batch, 64-token tile). 512 x 512 thr.
//    Flattened it=0..7 loop (sl=it>>2, fb=it&3), software-pipelined:
//      top: issue w2f_it -> GEMM1 (w1f from prev it) -> GELU -> Hsb[pb]
//      -> issue w1f_{it+1} -> lgkm-barrier -> GEMM2 (w2f_it long arrived).
// ---------------------------------------------------------------------------
__launch_bounds__(512, 4)
__global__ void k_moe_m(const float* __restrict__ xf,
                        const unsigned short* __restrict__ W1T,  // [E][F][D]
                        const unsigned short* __restrict__ W2T,  // [E][D][F]
                        const float* __restrict__ b1,
                        const float* __restrict__ b2,
                        const float* __restrict__ gamma,
                        const float* __restrict__ beta,
                        const float* __restrict__ route,
                        float* __restrict__ out) {
    __shared__ __align__(16) unsigned short Xsb[64][264];     // 33.8 KB
    __shared__ __align__(16) unsigned short Hsb[2][64][136];  // 34.8 KB dbuf
    __shared__ float gbuf[256], bbuf[256];
    __shared__ __align__(16) float rred[64][20];              // LN partials

    const int t = threadIdx.x;        // 0..511
    const int wv = t >> 6;            // wave 0..7
    const int lane = t & 63;
    const int g = lane >> 4;          // quad 0..3
    const int c = lane & 15;          // 0..15
    const int b = blockIdx.x & 7;     // XCD-aligned batch
    const int m0 = (blockIdx.x >> 3) * 64;

    if (t < 256) { gbuf[t] = gamma[t]; bbuf[t] = beta[t]; }

    const int e0i = (int)route[b * 4 + 0];
    const int e1i = (int)route[b * 4 + 1];
    const float rw0 = route[b * 4 + 2];
    const float rw1 = route[b * 4 + 3];

    // ---- stage X tile [64][256] as bf16, once (cvt_pk: 4 instr / 8 vals) --
    {
        int row = t >> 3;
        int col0 = (t & 7) * 32;
        const float* src = xf + ((size_t)(b * S_ + m0 + row) * D_ + col0);
        #pragma unroll
        for (int jg = 0; jg < 4; ++jg) {
            float4 a0 = *(const float4*)(src + jg * 8);
            float4 a1 = *(const float4*)(src + jg * 8 + 4);
            union { unsigned int pk[4]; uint4 q; } o;
            o.pk[0] = cvt_pk_bf16(a0.x, a0.y);
            o.pk[1] = cvt_pk_bf16(a0.z, a0.w);
            o.pk[2] = cvt_pk_bf16(a1.x, a1.y);
            o.pk[3] = cvt_pk_bf16(a1.z, a1.w);
            *(uint4*)&Xsb[row][col0 + jg * 8] = o.q;
        }
    }

    f32x4 Yacc[4][2];
    #pragma unroll
    for (int i = 0; i < 4; ++i)
        #pragma unroll
        for (int j = 0; j < 2; ++j)
            #pragma unroll
            for (int r = 0; r < 4; ++r) Yacc[i][j][r] = 0.f;

    // ---- prologue: issue w1f for it=0 (hidden under staging + barrier) ----
    bf16x8 w1f[8];
    {
        const unsigned short* w1p0 =
            W1T + ((size_t)(e0i * F_ + wv * 16 + c)) * D_ + g * 8;
        #pragma unroll
        for (int kc = 0; kc < 8; ++kc)
            w1f[kc] = *(const bf16x8*)(w1p0 + kc * 32);
    }

    bar_lds();   // Xsb visible to all waves; pins w1f issue

    int pb = 0;
    for (int it = 0; it < 8; ++it) {
        const int sl = it >> 2;
        const int fb = it & 3;
        const int e = sl ? e1i : e0i;
        const float w = sl ? rw1 : rw0;

        // ---- issue w2f for THIS iteration (first use: GEMM2, far below) --
        const unsigned short* w2p =
            W2T + ((size_t)(e * D_ + wv * 32 + c)) * F_ + fb * 128 + g * 8;
        bf16x8 w2f[4][2];
        #pragma unroll
        for (int kc = 0; kc < 4; ++kc)
            #pragma unroll
            for (int nt = 0; nt < 2; ++nt)
                w2f[kc][nt] = *(const bf16x8*)(w2p + (size_t)(nt * 16) * F_ + kc * 32);

        float bias1 = b1[e * F_ + fb * 128 + wv * 16 + c];

        // ---- GEMM1: H[64][128]; w1f was issued one iteration ago ----
        f32x4 Hacc[4];
        #pragma unroll
        for (int i = 0; i < 4; ++i)
            #pragma unroll
            for (int r = 0; r < 4; ++r) Hacc[i][r] = 0.f;
        #pragma unroll
        for (int kc = 0; kc < 8; ++kc) {
            #pragma unroll
            for (int mt = 0; mt < 4; ++mt) {
                bf16x8 a = *(const bf16x8*)&Xsb[mt * 16 + c][kc * 32 + g * 8];
                Hacc[mt] = __builtin_amdgcn_mfma_f32_16x16x32_bf16(a, w1f[kc], Hacc[mt], 0, 0, 0);
            }
        }

        // ---- GELU(+b1)*w -> Hsb[pb][64][128] (cvt_pk pairs) ----
        {
            const int col = wv * 16 + c;
            #pragma unroll
            for (int mt = 0; mt < 4; ++mt) {
                float h0 = w * gelu_f(Hacc[mt][0] + bias1);
                float h1 = w * gelu_f(Hacc[mt][1] + bias1);
                float h2 = w * gelu_f(Hacc[mt][2] + bias1);
                float h3 = w * gelu_f(Hacc[mt][3] + bias1);
                unsigned int q01 = cvt_pk_bf16(h0, h1);
                unsigned int q23 = cvt_pk_bf16(h2, h3);
                int rowb = mt * 16 + g * 4;
                Hsb[pb][rowb + 0][col] = (unsigned short)(q01 & 0xffffu);
                Hsb[pb][rowb + 1][col] = (unsigned short)(q01 >> 16);
                Hsb[pb][rowb + 2][col] = (unsigned short)(q23 & 0xffffu);
                Hsb[pb][rowb + 3][col] = (unsigned short)(q23 >> 16);
            }
        }

        // ---- issue w1f for NEXT iteration (hidden under barrier+GEMM2) ----
        {
            const int itn = (it + 1) & 7;
            const int en = (itn >> 2) ? e1i : e0i;
            const int fbn = itn & 3;
            const unsigned short* w1pn =
                W1T + ((size_t)(en * F_ + fbn * 128 + wv * 16 + c)) * D_ + g * 8;
            #pragma unroll
            for (int kc = 0; kc < 8; ++kc)
                w1f[kc] = *(const bf16x8*)(w1pn + kc * 32);
        }

        bar_lds();   // Hsb[pb] visible; all global loads stay in flight

        // ---- GEMM2: Y[64][256] += Hsb[pb] @ w2f ----
        #pragma unroll
        for (int kc = 0; kc < 4; ++kc) {
            #pragma unroll
            for (int mt = 0; mt < 4; ++mt) {
                bf16x8 a = *(const bf16x8*)&Hsb[pb][mt * 16 + c][kc * 32 + g * 8];
                #pragma unroll
                for (int nt = 0; nt < 2; ++nt)
                    Yacc[mt][nt] = __builtin_amdgcn_mfma_f32_16x16x32_bf16(a, w2f[kc][nt], Yacc[mt][nt], 0, 0, 0);
            }
        }
        pb ^= 1;
    }

    // ---- Epilogue: register LayerNorm ----
    // lane holds Y[row][d]: row = mt*16+g*4+r (16 rows), d = wv*32+nt*16+c.
    float bias2[2];
    #pragma unroll
    for (int nt = 0; nt < 2; ++nt) {
        int d = wv * 32 + nt * 16 + c;
        bias2[nt] = rw0 * b2[e0i * D_ + d] + rw1 * b2[e1i * D_ + d];
    }
    #pragma unroll
    for (int mt = 0; mt < 4; ++mt)
        #pragma unroll
        for (int r = 0; r < 4; ++r) {
            int row = mt * 16 + g * 4 + r;
            const float* xr = xf + (size_t)(b * S_ + m0 + row) * D_;
            float s = 0.f, sq = 0.f;
            #pragma unroll
            for (int nt = 0; nt < 2; ++nt) {
                int d = wv * 32 + nt * 16 + c;
                float v = Yacc[mt][nt][r] + bias2[nt] + xr[d];
                Yacc[mt][nt][r] = v;
                s += v; sq += v * v;
            }
            s += __shfl_xor(s, 1); sq += __shfl_xor(sq, 1);
            s += __shfl_xor(s, 2); sq += __shfl_xor(sq, 2);
            s += __shfl_xor(s, 4); sq += __shfl_xor(sq, 4);
            s += __shfl_xor(s, 8); sq += __shfl_xor(sq, 8);
            if (c == 0) { rred[row][wv * 2] = s; rred[row][wv * 2 + 1] = sq; }
        }
    bar_lds();
    #pragma unroll
    for (int mt = 0; mt < 4; ++mt)
        #pragma unroll
        for (int r = 0; r < 4; ++r) {
            int row = mt * 16 + g * 4 + r;
            float4 p0 = *(const float4*)&rred[row][0];
            float4 p1 = *(const float4*)&rred[row][4];
            float4 p2 = *(const float4*)&rred[row][8];
            float4 p3 = *(const float4*)&rred[row][12];
            float s  = ((p0.x + p1.x) + (p2.x + p3.x)) + ((p0.z + p1.z) + (p2.z + p3.z));
            float sq = ((p0.y + p1.y) + (p2.y + p3.y)) + ((p0.w + p1.w) + (p2.w + p3.w));
            float mu = s * (1.0f / 256.0f);
            float var = sq * (1.0f / 256.0f) - mu * mu;
            float rstd = rsqrtf(var + 1e-5f);
            float* op = out + (size_t)(b * S_ + m0 + row) * D_;
            #pragma unroll
            for (int nt = 0; nt < 2; ++nt) {
                int d = wv * 32 + nt * 16 + c;
                op[d] = (Yacc[mt][nt][r] - mu) * rstd * gbuf[d] + bbuf[d];
            }
        }
}

// ---------------------------------------------------------------------------
extern "C" void kernel_launch(void* const* d_in, const int* in_sizes, int n_in,
                              void* d_out, int out_size, void* d_ws, size_t ws_size,
                              hipStream_t stream) {
    const float* x     = (const float*)d_in[0];
    const float* Wr    = (const float*)d_in[1];
    const float* br    = (const float*)d_in[2];
    const float* W1    = (const float*)d_in[3];
    const float* b1    = (const float*)d_in[4];
    const float* W2    = (const float*)d_in[5];
    const float* b2    = (const float*)d_in[6];
    const float* gamma = (const float*)d_in[7];
    const float* beta  = (const float*)d_in[8];
    float* out = (float*)d_out;

    char* ws = (char*)d_ws;
    double* partial = (double*)ws;                               // 1 MB
    float* route  = (float*)(ws + 1064960);                      // 128 B
    unsigned short* W1T = (unsigned short*)(ws + 1081344);       // 2 MB [E][F][D]
    unsigned short* W2T = (unsigned short*)(ws + 3178496);       // 2 MB [E][D][F]
    // total ws usage: ~5.3 MB

    hipLaunchKernelGGL(k_prep, dim3(2560), dim3(256), 0, stream,
                       x, partial, W1, W2, W1T, W2T);
    hipLaunchKernelGGL(k_finish, dim3(1), dim3(1024), 0, stream,
                       partial, Wr, br, route);
    hipLaunchKernelGGL(k_moe_m, dim3(512), dim3(512), 0, stream,
                       x, W1T, W2T, b1, b2, gamma, beta, route, out);
}

// Round 5
// 201.936 us; speedup vs baseline: 1.5544x; 1.0570x over previous
//
#include <hip/hip_runtime.h>
#include <math.h>

// ---------------------------------------------------------------------------
// SparseMoE — MFMA kernel, MI355X (gfx950).  B=8 S=4096 D=256 F=512 E=8 K=2.
// r14 (from r13 @ 213.4us, k_moe_m 95.2us, MfmaUtil 15.0, conflicts 6.68M):
//   * GEMM1 operand swap: mfma(w1f, x_frag) computes H^T with the SAME
//     registers (A-frag and B-frag lane layouts are identical). Lane now
//     owns 4 consecutive f for one token -> Hsb write is ONE b64 store per
//     mt (was 16 scalar u16 stores/iter with same-dword RMW conflicts).
//     bias1 becomes a float4 load. Arithmetic per element unchanged.
//   * k_finish split: k_red2 (8 blocks, 1/batch — the 1MB fp64 partial read
//     was serialized on ONE CU ~30-35us) + k_router (1 tiny block, same
//     fp64 phases). Same summation order everywhere.
// Router fp64 deterministic. ws ~5.3 MB.
// ---------------------------------------------------------------------------

#define B_ 8
#define S_ 4096
#define D_ 256
#define F_ 512
#define E_ 8

typedef short bf16x8 __attribute__((ext_vector_type(8)));
typedef float f32x4 __attribute__((ext_vector_type(4)));

static __device__ __forceinline__ unsigned short f2bf(float f) {
    union { float f; unsigned int i; } v; v.f = f;
    unsigned int x = v.i;
    return (unsigned short)((x + 0x7fffu + ((x >> 16) & 1u)) >> 16);  // RNE
}

// pack two f32 -> two bf16 (RNE), lo = s0, hi = s1
static __device__ __forceinline__ unsigned int cvt_pk_bf16(float s0, float s1) {
    unsigned int r;
    asm("v_cvt_pk_bf16_f32 %0, %1, %2" : "=v"(r) : "v"(s0), "v"(s1));
    return r;
}

// barrier that drains LDS ops only — global loads stay in flight.
static __device__ __forceinline__ void bar_lds() {
    asm volatile("s_waitcnt lgkmcnt(0)" ::: "memory");
    __builtin_amdgcn_s_barrier();
}

// GELU(v) = 0.5 v (1 + erf(v/sqrt2)); erf via A&S 7.1.26, |err|<=1.5e-7.
static __device__ __forceinline__ float gelu_f(float v) {
    float x = fabsf(v) * 0.70710678118654752f;
    float t = __builtin_amdgcn_rcpf(1.0f + 0.3275911f * x);
    float p = t * (0.254829592f +
              t * (-0.284496736f +
              t * (1.421413741f +
              t * (-1.453152027f +
              t * 1.061405429f))));
    float er = 1.0f - p * __expf(-x * x);
    er = __builtin_copysignf(er, v);
    return 0.5f * v * (1.0f + er);
}

// ---------------------------------------------------------------------------
// 1) k_prep: fused grid. Blocks [0,512): fp64 partial mean-reduction over S.
//    Blocks [512,1536): W1 [E][256][512] -> W1T [E][512][256] bf16.
//    Blocks [1536,2560): W2 [E][512][256] -> W2T [E][256][512] bf16.
// ---------------------------------------------------------------------------
__global__ void k_prep(const float* __restrict__ x,
                       double* __restrict__ partial,
                       const float* __restrict__ W1,
                       const float* __restrict__ W2,
                       unsigned short* __restrict__ W1T,
                       unsigned short* __restrict__ W2T) {
    int bid = blockIdx.x;
    if (bid < 512) {
        int b = bid >> 6;
        int c = bid & 63;
        int d = threadIdx.x;
        const float* p = x + ((size_t)(b * S_ + c * 64) * D_ + d);
        double acc = 0.0;
        #pragma unroll 8
        for (int i = 0; i < 64; ++i) acc += (double)p[(size_t)i * D_];
        partial[(size_t)bid * D_ + d] = acc;
        return;
    }
    __shared__ float tile[32][33];
    const float* src;
    unsigned short* dst;
    int R, C, cb, rb;
    if (bid < 1536) {
        int b2 = bid - 512;            // e(8) x by(8) x bx(16)
        int e = b2 >> 7, rem = b2 & 127;
        int by = rem >> 4, bx = rem & 15;
        R = 256; C = 512;
        src = W1 + (size_t)e * R * C;
        dst = W1T + (size_t)e * R * C;
        cb = bx * 32; rb = by * 32;
    } else {
        int b2 = bid - 1536;           // e(8) x by(16) x bx(8)
        int e = b2 >> 7, rem = b2 & 127;
        int by = rem >> 3, bx = rem & 7;
        R = 512; C = 256;
        src = W2 + (size_t)e * R * C;
        dst = W2T + (size_t)e * R * C;
        cb = bx * 32; rb = by * 32;
    }
    int tx = threadIdx.x & 31, ty = threadIdx.x >> 5;
    #pragma unroll
    for (int k = 0; k < 4; ++k)
        tile[ty + 8 * k][tx] = src[(size_t)(rb + ty + 8 * k) * C + cb + tx];
    __syncthreads();
    #pragma unroll
    for (int k = 0; k < 4; ++k)
        dst[(size_t)(cb + ty + 8 * k) * R + rb + tx] = f2bf(tile[tx][ty + 8 * k]);
}

// ---------------------------------------------------------------------------
// 2a) k_red2: 8 blocks (one per batch). Block bb: xs[d] = sum_c partial,
//     then logits lg[bb*8+e] (same fp64 order as r13's k_finish).
// ---------------------------------------------------------------------------
__global__ void k_red2(const double* __restrict__ partial,
                       const float* __restrict__ Wr,
                       const float* __restrict__ br,
                       double* __restrict__ lgout) {
    __shared__ double xs[256];
    int bb = blockIdx.x;
    int t = threadIdx.x;              // 0..255 = d
    double acc = 0.0;
    #pragma unroll 8
    for (int c = 0; c < 64; ++c)
        acc += partial[(size_t)(bb * 64 + c) * D_ + t];
    xs[t] = acc;
    __syncthreads();
    if (t < 8) {
        int e = t;
        double a2 = 0.0;
        for (int d = 0; d < D_; ++d)
            a2 += (xs[d] * (1.0 / (double)S_)) * (double)Wr[d * E_ + e];
        lgout[bb * 8 + e] = a2 + (double)br[e];
    }
}

// ---------------------------------------------------------------------------
// 2b) k_router: 1 tiny block. Identical fp64 phases A/B to r13's k_finish.
// ---------------------------------------------------------------------------
__global__ void k_router(const double* __restrict__ lgin,
                         float* __restrict__ route) {
    __shared__ double lg[64];
    __shared__ double rw[8][8];
    int t = threadIdx.x;
    if (t < 64) lg[t] = lgin[t];
    __syncthreads();
    if (t < 8) {
        int bb = t;
        double m = -1e300;
        for (int ee = 0; ee < 8; ++ee) m = fmax(m, lg[bb * 8 + ee]);
        double s = 0.0;
        double p[8];
        for (int ee = 0; ee < 8; ++ee) { p[ee] = exp(lg[bb * 8 + ee] - m); s += p[ee]; }
        for (int ee = 0; ee < 8; ++ee) rw[bb][ee] = p[ee] / s;
    }
    __syncthreads();
    if (t < 8) {
        int bb = t;
        const double capacity = 5120.0;
        double scale[8];
        for (int ee = 0; ee < 8; ++ee) {
            double load = 0.0;
            for (int b2 = 0; b2 < 8; ++b2) load += rw[b2][ee];
            load *= 4096.0;
            scale[ee] = load > capacity ? capacity / load : 1.0;
        }
        double v[8];
        double m = -1e300;
        for (int ee = 0; ee < 8; ++ee) { v[ee] = rw[bb][ee] * scale[ee]; m = fmax(m, v[ee]); }
        double s = 0.0;
        for (int ee = 0; ee < 8; ++ee) { v[ee] = exp(v[ee] - m); s += v[ee]; }
        for (int ee = 0; ee < 8; ++ee) v[ee] /= s;
        int i1 = 0;
        for (int ee = 1; ee < 8; ++ee) if (v[ee] > v[i1]) i1 = ee;
        int i2 = (i1 == 0) ? 1 : 0;
        for (int ee = 0; ee < 8; ++ee) { if (ee == i1) continue; if (v[ee] > v[i2]) i2 = ee; }
        double d21 = v[i2] - v[i1];
        double ed = exp(d21);
        double w1 = 1.0 / (1.0 + ed);
        double w2 = ed * w1;
        route[bb * 4 + 0] = (float)i1;
        route[bb * 4 + 1] = (float)i2;
        route[bb * 4 + 2] = (float)w1;
        route[bb * 4 + 3] = (float)w2;
    }
}

// ---------------------------------------------------------------------------
// 3) Main MFMA kernel: per block = (batch, 64-token tile). 512 x 512 thr.
//    Flattened it=0..7 loop (sl=it>>2, fb=it&3), software-pipelined:
//      top: issue w2f_it -> GEMM1 (SWAPPED: mfma(w1f, x) -> H^T ownership,
//      lane holds 4 consecutive f per token) -> GELU -> ONE b64 Hsb store
//      per mt -> issue w1f_{it+1} -> lgkm-barrier -> GEMM2.
// ---------------------------------------------------------------------------
__launch_bounds__(512, 4)
__global__ void k_moe_m(const float* __restrict__ xf,
                        const unsigned short* __restrict__ W1T,  // [E][F][D]
                        const unsigned short* __restrict__ W2T,  // [E][D][F]
                        const float* __restrict__ b1,
                        const float* __restrict__ b2,
                        const float* __restrict__ gamma,
                        const float* __restrict__ beta,
                        const float* __restrict__ route,
                        float* __restrict__ out) {
    __shared__ __align__(16) unsigned short Xsb[64][264];     // 33.8 KB
    __shared__ __align__(16) unsigned short Hsb[2][64][136];  // 34.8 KB dbuf
    __shared__ float gbuf[256], bbuf[256];
    __shared__ __align__(16) float rred[64][20];              // LN partials

    const int t = threadIdx.x;        // 0..511
    const int wv = t >> 6;            // wave 0..7
    const int lane = t & 63;
    const int g = lane >> 4;          // quad 0..3
    const int c = lane & 15;          // 0..15
    const int b = blockIdx.x & 7;     // XCD-aligned batch
    const int m0 = (blockIdx.x >> 3) * 64;

    if (t < 256) { gbuf[t] = gamma[t]; bbuf[t] = beta[t]; }

    const int e0i = (int)route[b * 4 + 0];
    const int e1i = (int)route[b * 4 + 1];
    const float rw0 = route[b * 4 + 2];
    const float rw1 = route[b * 4 + 3];

    // ---- stage X tile [64][256] as bf16, once (cvt_pk: 4 instr / 8 vals) --
    {
        int row = t >> 3;
        int col0 = (t & 7) * 32;
        const float* src = xf + ((size_t)(b * S_ + m0 + row) * D_ + col0);
        #pragma unroll
        for (int jg = 0; jg < 4; ++jg) {
            float4 a0 = *(const float4*)(src + jg * 8);
            float4 a1 = *(const float4*)(src + jg * 8 + 4);
            union { unsigned int pk[4]; uint4 q; } o;
            o.pk[0] = cvt_pk_bf16(a0.x, a0.y);
            o.pk[1] = cvt_pk_bf16(a0.z, a0.w);
            o.pk[2] = cvt_pk_bf16(a1.x, a1.y);
            o.pk[3] = cvt_pk_bf16(a1.z, a1.w);
            *(uint4*)&Xsb[row][col0 + jg * 8] = o.q;
        }
    }

    f32x4 Yacc[4][2];
    #pragma unroll
    for (int i = 0; i < 4; ++i)
        #pragma unroll
        for (int j = 0; j < 2; ++j)
            #pragma unroll
            for (int r = 0; r < 4; ++r) Yacc[i][j][r] = 0.f;

    // ---- prologue: issue w1f for it=0 (hidden under staging + barrier) ----
    bf16x8 w1f[8];
    {
        const unsigned short* w1p0 =
            W1T + ((size_t)(e0i * F_ + wv * 16 + c)) * D_ + g * 8;
        #pragma unroll
        for (int kc = 0; kc < 8; ++kc)
            w1f[kc] = *(const bf16x8*)(w1p0 + kc * 32);
    }

    bar_lds();   // Xsb visible to all waves; pins w1f issue

    int pb = 0;
    for (int it = 0; it < 8; ++it) {
        const int sl = it >> 2;
        const int fb = it & 3;
        const int e = sl ? e1i : e0i;
        const float w = sl ? rw1 : rw0;

        // ---- issue w2f for THIS iteration (first use: GEMM2, far below) --
        const unsigned short* w2p =
            W2T + ((size_t)(e * D_ + wv * 32 + c)) * F_ + fb * 128 + g * 8;
        bf16x8 w2f[4][2];
        #pragma unroll
        for (int kc = 0; kc < 4; ++kc)
            #pragma unroll
            for (int nt = 0; nt < 2; ++nt)
                w2f[kc][nt] = *(const bf16x8*)(w2p + (size_t)(nt * 16) * F_ + kc * 32);

        // bias for this lane's 4 consecutive f rows (H^T ownership)
        float4 bias4 = *(const float4*)&b1[e * F_ + fb * 128 + wv * 16 + g * 4];

        // ---- GEMM1 (swapped): H^T[f][token]; lane holds 4 f x 1 token ----
        f32x4 Hacc[4];
        #pragma unroll
        for (int i = 0; i < 4; ++i)
            #pragma unroll
            for (int r = 0; r < 4; ++r) Hacc[i][r] = 0.f;
        #pragma unroll
        for (int kc = 0; kc < 8; ++kc) {
            #pragma unroll
            for (int mt = 0; mt < 4; ++mt) {
                bf16x8 a = *(const bf16x8*)&Xsb[mt * 16 + c][kc * 32 + g * 8];
                Hacc[mt] = __builtin_amdgcn_mfma_f32_16x16x32_bf16(w1f[kc], a, Hacc[mt], 0, 0, 0);
            }
        }

        // ---- GELU(+b1)*w -> Hsb[pb][token][f], ONE b64 store per mt ----
        #pragma unroll
        for (int mt = 0; mt < 4; ++mt) {
            float h0 = w * gelu_f(Hacc[mt][0] + bias4.x);
            float h1 = w * gelu_f(Hacc[mt][1] + bias4.y);
            float h2 = w * gelu_f(Hacc[mt][2] + bias4.z);
            float h3 = w * gelu_f(Hacc[mt][3] + bias4.w);
            uint2 q;
            q.x = cvt_pk_bf16(h0, h1);
            q.y = cvt_pk_bf16(h2, h3);
            *(uint2*)&Hsb[pb][mt * 16 + c][wv * 16 + g * 4] = q;
        }

        // ---- issue w1f for NEXT iteration (hidden under barrier+GEMM2) ----
        {
            const int itn = (it + 1) & 7;
            const int en = (itn >> 2) ? e1i : e0i;
            const int fbn = itn & 3;
            const unsigned short* w1pn =
                W1T + ((size_t)(en * F_ + fbn * 128 + wv * 16 + c)) * D_ + g * 8;
            #pragma unroll
            for (int kc = 0; kc < 8; ++kc)
                w1f[kc] = *(const bf16x8*)(w1pn + kc * 32);
        }

        bar_lds();   // Hsb[pb] visible; all global loads stay in flight

        // ---- GEMM2: Y[64][256] += Hsb[pb] @ w2f ----
        #pragma unroll
        for (int kc = 0; kc < 4; ++kc) {
            #pragma unroll
            for (int mt = 0; mt < 4; ++mt) {
                bf16x8 a = *(const bf16x8*)&Hsb[pb][mt * 16 + c][kc * 32 + g * 8];
                #pragma unroll
                for (int nt = 0; nt < 2; ++nt)
                    Yacc[mt][nt] = __builtin_amdgcn_mfma_f32_16x16x32_bf16(a, w2f[kc][nt], Yacc[mt][nt], 0, 0, 0);
            }
        }
        pb ^= 1;
    }

    // ---- Epilogue: register LayerNorm ----
    // lane holds Y[row][d]: row = mt*16+g*4+r (16 rows), d = wv*32+nt*16+c.
    float bias2[2];
    #pragma unroll
    for (int nt = 0; nt < 2; ++nt) {
        int d = wv * 32 + nt * 16 + c;
        bias2[nt] = rw0 * b2[e0i * D_ + d] + rw1 * b2[e1i * D_ + d];
    }
    #pragma unroll
    for (int mt = 0; mt < 4; ++mt)
        #pragma unroll
        for (int r = 0; r < 4; ++r) {
            int row = mt * 16 + g * 4 + r;
            const float* xr = xf + (size_t)(b * S_ + m0 + row) * D_;
            float s = 0.f, sq = 0.f;
            #pragma unroll
            for (int nt = 0; nt < 2; ++nt) {
                int d = wv * 32 + nt * 16 + c;
                float v = Yacc[mt][nt][r] + bias2[nt] + xr[d];
                Yacc[mt][nt][r] = v;
                s += v; sq += v * v;
            }
            s += __shfl_xor(s, 1); sq += __shfl_xor(sq, 1);
            s += __shfl_xor(s, 2); sq += __shfl_xor(sq, 2);
            s += __shfl_xor(s, 4); sq += __shfl_xor(sq, 4);
            s += __shfl_xor(s, 8); sq += __shfl_xor(sq, 8);
            if (c == 0) { rred[row][wv * 2] = s; rred[row][wv * 2 + 1] = sq; }
        }
    bar_lds();
    #pragma unroll
    for (int mt = 0; mt < 4; ++mt)
        #pragma unroll
        for (int r = 0; r < 4; ++r) {
            int row = mt * 16 + g * 4 + r;
            float4 p0 = *(const float4*)&rred[row][0];
            float4 p1 = *(const float4*)&rred[row][4];
            float4 p2 = *(const float4*)&rred[row][8];
            float4 p3 = *(const float4*)&rred[row][12];
            float s  = ((p0.x + p1.x) + (p2.x + p3.x)) + ((p0.z + p1.z) + (p2.z + p3.z));
            float sq = ((p0.y + p1.y) + (p2.y + p3.y)) + ((p0.w + p1.w) + (p2.w + p3.w));
            float mu = s * (1.0f / 256.0f);
            float var = sq * (1.0f / 256.0f) - mu * mu;
            float rstd = rsqrtf(var + 1e-5f);
            float* op = out + (size_t)(b * S_ + m0 + row) * D_;
            #pragma unroll
            for (int nt = 0; nt < 2; ++nt) {
                int d = wv * 32 + nt * 16 + c;
                op[d] = (Yacc[mt][nt][r] - mu) * rstd * gbuf[d] + bbuf[d];
            }
        }
}

// ---------------------------------------------------------------------------
extern "C" void kernel_launch(void* const* d_in, const int* in_sizes, int n_in,
                              void* d_out, int out_size, void* d_ws, size_t ws_size,
                              hipStream_t stream) {
    const float* x     = (const float*)d_in[0];
    const float* Wr    = (const float*)d_in[1];
    const float* br    = (const float*)d_in[2];
    const float* W1    = (const float*)d_in[3];
    const float* b1    = (const float*)d_in[4];
    const float* W2    = (const float*)d_in[5];
    const float* b2    = (const float*)d_in[6];
    const float* gamma = (const float*)d_in[7];
    const float* beta  = (const float*)d_in[8];
    float* out = (float*)d_out;

    char* ws = (char*)d_ws;
    double* partial = (double*)ws;                               // 1 MB
    float* route  = (float*)(ws + 1064960);                      // 128 B
    double* lg    = (double*)(ws + 1065472);                     // 512 B
    unsigned short* W1T = (unsigned short*)(ws + 1081344);       // 2 MB [E][F][D]
    unsigned short* W2T = (unsigned short*)(ws + 3178496);       // 2 MB [E][D][F]
    // total ws usage: ~5.3 MB

    hipLaunchKernelGGL(k_prep, dim3(2560), dim3(256), 0, stream,
                       x, partial, W1, W2, W1T, W2T);
    hipLaunchKernelGGL(k_red2, dim3(8), dim3(256), 0, stream,
                       partial, Wr, br, lg);
    hipLaunchKernelGGL(k_router, dim3(1), dim3(64), 0, stream,
                       lg, route);
    hipLaunchKernelGGL(k_moe_m, dim3(512), dim3(512), 0, stream,
                       x, W1T, W2T, b1, b2, gamma, beta, route, out);
}